// Round 2
// baseline (346.121 us; speedup 1.0000x reference)
//
#include <hip/hip_runtime.h>

// RocketConv: depthwise dilated conv, 84 fixed ternary kernels.
// x: (B=16, C=16, T=4096) fp32 -> out flat layout ((b*C + c)*K + k)*T + t.
// y_k[t] = 3*(tap[a]+tap[b]+tap[c]) - S, taps at x[t + 4*j - 16] (zero pad).
//
// Write-path design:
//  - Each block owns one (b,c) and 21 CONSECUTIVE k-rows over the FULL T=4096,
//    so it emits one contiguous 336 KB stream (fillBuffer hits 6.2 TB/s with
//    exactly this pattern; 1KB-chunks-at-16KB-stride measured ~3.2 TB/s).
//  - Nontemporal stores: output has zero reuse; avoid L2 write-allocate thrash
//    (352 MB streaming through 4 MB/XCD L2).
//  - k-group dispatched via switch -> templated body so COMBS indices fold at
//    compile time and tap[][] stays in registers (no scratch, rule #20).

#define KLEN 9
#define NK   84
#define BB   16
#define CC   16
#define TT   4096
#define HALO 16
#define KG   4                  // k-groups per (b,c)
#define KPB  (NK / KG)          // 21 consecutive rows per block
#define NTHR 512
#define LDS_N (TT + 2 * HALO)   // 4128 floats = 16.5 KB

typedef float f4 __attribute__((ext_vector_type(4)));

struct CombTable { int a[NK], b[NK], c[NK]; };
constexpr CombTable make_combs() {
    CombTable t{};
    int n = 0;
    for (int i = 0; i < KLEN; ++i)
        for (int j = i + 1; j < KLEN; ++j)
            for (int k = j + 1; k < KLEN; ++k) {
                t.a[n] = i; t.b[n] = j; t.c[n] = k; ++n;
            }
    return t;
}
constexpr CombTable COMBS = make_combs();  // lexicographic == itertools.combinations

template <int K0>
__device__ __forceinline__ void emit_rows(const f4 (&tap)[2][KLEN],
                                          const f4 (&s)[2],
                                          float* __restrict__ obase) {
#pragma unroll
    for (int n = 0; n < KPB; ++n) {
        const int ia = COMBS.a[K0 + n];   // compile-time under full unroll
        const int ib = COMBS.b[K0 + n];
        const int ic = COMBS.c[K0 + n];
#pragma unroll
        for (int g = 0; g < 2; ++g) {
            f4 r = (tap[g][ia] + tap[g][ib] + tap[g][ic]) * 3.0f - s[g];
            __builtin_nontemporal_store(
                r, (f4*)(obase + (size_t)n * TT + g * (NTHR * 4)));
        }
    }
}

__global__ __launch_bounds__(NTHR) void rocket_conv(const float* __restrict__ x,
                                                    float* __restrict__ out) {
    __shared__ __align__(16) float lds[LDS_N];

    const int tid = threadIdx.x;
    const int kg  = blockIdx.x;   // 0..3
    const int c   = blockIdx.y;   // 0..15
    const int b   = blockIdx.z;   // 0..15

    // Stage the full channel (+ zero halo) into LDS. lds[i] = x[t = i - HALO].
    const float* xbc = x + ((size_t)b * CC + c) * TT;
    *(f4*)&lds[HALO + 4 * tid]          = *(const f4*)&xbc[4 * tid];
    *(f4*)&lds[HALO + 4 * (tid + NTHR)] = *(const f4*)&xbc[4 * (tid + NTHR)];
    if (tid < HALO) {
        lds[tid] = 0.0f;               // left pad  [0..15]
        lds[HALO + TT + tid] = 0.0f;   // right pad [4112..4127]
    }
    __syncthreads();

    // Each thread owns 4 consecutive t at two positions: t = 4*tid + 2048*g.
    // tap_j(t) = x[t + 4j - 16] = lds[t + 4j].
    f4 tap[2][KLEN];
    f4 s[2];
#pragma unroll
    for (int g = 0; g < 2; ++g) {
        const int t0 = 4 * tid + (NTHR * 4) * g;
#pragma unroll
        for (int j = 0; j < KLEN; ++j) tap[g][j] = *(const f4*)&lds[t0 + 4 * j];
        f4 acc = tap[g][0];
#pragma unroll
        for (int j = 1; j < KLEN; ++j) acc += tap[g][j];
        s[g] = acc;
    }

    // Output rows k = kg*21 .. kg*21+20 are adjacent: block writes one
    // contiguous 21 * 16 KB = 336 KB region.
    float* obase = out + ((size_t)(b * CC + c) * NK + (size_t)kg * KPB) * TT
                       + 4 * tid;
    switch (kg & 3) {
        case 0: emit_rows<0 * KPB>(tap, s, obase); break;
        case 1: emit_rows<1 * KPB>(tap, s, obase); break;
        case 2: emit_rows<2 * KPB>(tap, s, obase); break;
        default: emit_rows<3 * KPB>(tap, s, obase); break;
    }
}

extern "C" void kernel_launch(void* const* d_in, const int* in_sizes, int n_in,
                              void* d_out, int out_size, void* d_ws, size_t ws_size,
                              hipStream_t stream) {
    (void)in_sizes; (void)n_in; (void)d_ws; (void)ws_size; (void)out_size;
    const float* x = (const float*)d_in[0];
    float* out     = (float*)d_out;
    dim3 grid(KG, CC, BB);   // 4 x 16 x 16 = 1024 blocks, 512 threads each
    rocket_conv<<<grid, NTHR, 0, stream>>>(x, out);
}